// Round 1
// 456.172 us; speedup vs baseline: 1.1703x; 1.1703x over previous
//
#include <hip/hip_runtime.h>
#include <hip/hip_bf16.h>
#include <stdint.h>

// Problem constants (fixed by setup_inputs)
#define M_TOT 8192
#define N_TOT 4096
#define K_TOT 4096
#define GROUP 128

// Round-2 lesson: fp16 reference arrays arrive as FLOAT32 ("else float*" rule).
// Round-4 lesson: fused one-pass is barrier/latency-bound; two-pass wins.
// Round-5 lesson: XOR chunk swizzle on global side of global_load_lds ->
//   0 LDS bank conflicts (measured).
// Round-6 (this round): m97 structure plateaued at 806 TF (MfmaUtil 36%).
//   Port GEMM to the 256^2 8-phase template (T3+T4 counted vmcnt, T5 setprio):
//   4 phases/K-tile, stage A(t+1) at ph0/1 (buf^1), B(t+2) at ph2/3 (buf,
//   legal: B(t) fully consumed at ph0), single vmcnt(4) per K-tile boundary.

using f32x4  = __attribute__((ext_vector_type(4))) float;
using bf16x8 = __attribute__((ext_vector_type(8))) __bf16;

typedef __attribute__((address_space(3))) void as3_void;
typedef const __attribute__((address_space(1))) void as1_void;

// ---------------- pass 1a: cast x f32 -> bf16 (one-shot) ----------------
__global__ __launch_bounds__(256) void cast_x(const float* __restrict__ x,
                                              __bf16* __restrict__ xb) {
    const size_t t = (size_t)blockIdx.x * 256 + threadIdx.x;
    const float4 f0 = *(const float4*)(x + t * 8);
    const float4 f1 = *(const float4*)(x + t * 8 + 4);
    bf16x8 v;
    v[0]=(__bf16)f0.x; v[1]=(__bf16)f0.y; v[2]=(__bf16)f0.z; v[3]=(__bf16)f0.w;
    v[4]=(__bf16)f1.x; v[5]=(__bf16)f1.y; v[6]=(__bf16)f1.z; v[7]=(__bf16)f1.w;
    *(bf16x8*)(xb + t * 8) = v;
}

// ------- pass 1b: dequant qweight -> Wt [N][K] bf16 (LDS transpose) -------
__global__ __launch_bounds__(256) void dequant_w(
    const int*   __restrict__ qweight,  // [K/8, N]
    const int*   __restrict__ qzeros,   // [G, N/8]
    const float* __restrict__ scales,   // [G, N]
    const int*   __restrict__ g_idx,    // [K]
    __bf16* __restrict__ Wt)            // [N, K]
{
    __shared__ __align__(16) unsigned short T[64 * 72];  // [64n][72k]
    const int k0  = blockIdx.x * 64;
    const int n0  = blockIdx.y * 64;
    const int g   = g_idx[k0];          // 64-k tile sits in one group (64 | 128)
    const int tid = threadIdx.x;

    #pragma unroll
    for (int i = 0; i < 2; ++i) {
        const int idx = tid + i * 256;  // 0..511
        const int r   = idx >> 6;       // 0..7  (8 k's each)
        const int n   = idx & 63;
        const int qi  = qweight[(size_t)((k0 >> 3) + r) * N_TOT + n0 + n];
        const int zi  = qzeros[g * (N_TOT / 8) + ((n0 + n) >> 3)];
        const float s = scales[g * N_TOT + n0 + n];
        const float zs = (float)(((zi >> ((n & 7) * 4)) & 0xF) + 1) * s;
        bf16x8 v;
        #pragma unroll
        for (int j = 0; j < 8; ++j)
            v[j] = (__bf16)((float)((qi >> (4 * j)) & 0xF) * s - zs);  // (w-z-1)*s
        *(bf16x8*)&T[n * 72 + r * 8] = v;
    }
    __syncthreads();

    const int n = tid >> 2;             // 0..63
    const int c = (tid & 3) * 16;       // 0,16,32,48
    const bf16x8 a = *(const bf16x8*)&T[n * 72 + c];
    const bf16x8 b = *(const bf16x8*)&T[n * 72 + c + 8];
    __bf16* dst = Wt + (size_t)(n0 + n) * K_TOT + k0 + c;
    *(bf16x8*)dst = a;
    *(bf16x8*)(dst + 8) = b;
}

// ------- pass 2: 256^2 8-phase bf16 GEMM (B^T), XOR-swizzled LDS -------
#define GBM 256
#define GBN 256
#define GBK 64
#define NKT (K_TOT / GBK)   // 64

#define BAR() do { asm volatile("" ::: "memory"); \
                   __builtin_amdgcn_s_barrier();  \
                   asm volatile("" ::: "memory"); } while (0)
#define WAIT_LGKM0() asm volatile("s_waitcnt lgkmcnt(0)" ::: "memory")
#define WAIT_VM4()   asm volatile("s_waitcnt vmcnt(4)"   ::: "memory")
#define WAIT_VM0()   asm volatile("s_waitcnt vmcnt(0)"   ::: "memory")

// Phase q (q=1..3): read A-quadrant, issue one half-tile stage, barrier,
// lgkmcnt(0), 16 MFMA under setprio(1), barrier.
#define GPHASE(q, STAGE_STMT)                                                 \
    {                                                                         \
        bf16x8 av[2][2];                                                      \
        _Pragma("unroll")                                                     \
        for (int ks = 0; ks < 2; ++ks) {                                      \
            av[0][ks] = ldA(buf, 2 * (q), ks);                                \
            av[1][ks] = ldA(buf, 2 * (q) + 1, ks);                            \
        }                                                                     \
        STAGE_STMT;                                                           \
        BAR();                                                                \
        WAIT_LGKM0();                                                         \
        __builtin_amdgcn_s_setprio(1);                                        \
        _Pragma("unroll")                                                     \
        for (int ks = 0; ks < 2; ++ks)                                        \
            _Pragma("unroll")                                                 \
            for (int mtl = 0; mtl < 2; ++mtl)                                 \
                _Pragma("unroll")                                             \
                for (int nt = 0; nt < 4; ++nt)                                \
                    acc[2 * (q) + mtl][nt] =                                  \
                        __builtin_amdgcn_mfma_f32_16x16x32_bf16(              \
                            av[mtl][ks], bv[nt][ks], acc[2 * (q) + mtl][nt],  \
                            0, 0, 0);                                         \
        __builtin_amdgcn_s_setprio(0);                                        \
        BAR();                                                                \
    }

__global__ __launch_bounds__(512, 2) void gemm8p(
    const __bf16* __restrict__ xb,   // [M, K]
    const __bf16* __restrict__ Wt,   // [N, K]
    const float*  __restrict__ bias, // [N]
    float* __restrict__ out)         // [M, N]
{
    // [buf][mat: 0=A,1=B][256 rows * 64 k] ushort = 128 KiB total
    __shared__ __align__(16) unsigned short LDS[2][2][GBM * GBK];

    const int tid  = threadIdx.x;
    const int wid  = tid >> 6;
    const int lane = tid & 63;
    const int l15  = lane & 15;
    const int quad = lane >> 4;

    // XCD-aware bijective swizzle (nwg = 512, divisible by 8)
    int bid = blockIdx.x;
    bid = (bid & 7) * (512 >> 3) + (bid >> 3);
    const int tn = bid & (N_TOT / GBN - 1);   // 0..15
    const int tm = bid >> 4;                  // 0..31
    const int m0 = tm * GBM;
    const int n0 = tn * GBN;

    const int wm = (wid >> 2) * 128;  // 0 or 128 (M-wave)
    const int wn = (wid & 3) * 64;    // 0..192   (N-wave)

    f32x4 acc[8][4];
    #pragma unroll
    for (int i = 0; i < 8; ++i)
        #pragma unroll
        for (int j = 0; j < 4; ++j)
            acc[i][j] = (f32x4)0.f;

    // Stage one half-tile (128 rows x 64 k) of mat into LDS[bf][mat], half h.
    // 2 x global_load_lds (16B) per thread. Chunk c holds global k-chunk
    // (c&7)^(row&7): LDS dst stays lane-linear, swizzle applied on global src.
    auto stage = [&](int bf, int mat, int h, const __bf16* __restrict__ base,
                     int row0, int kt) {
        #pragma unroll
        for (int j = 0; j < 2; ++j) {
            const int c  = j * 512 + tid;          // 0..1023 chunk id
            const int rl = c >> 3;                 // 0..127 row in half
            const int kc = (c & 7) ^ (rl & 7);     // XOR swizzle (global side)
            const __bf16* ga = base + (size_t)(row0 + h * 128 + rl) * K_TOT
                             + kt * GBK + kc * 8;
            __builtin_amdgcn_global_load_lds((as1_void*)ga,
                (as3_void*)&LDS[bf][mat][h * 8192 + (j * 512 + wid * 64) * 8],
                16, 0, 0);
        }
    };
    auto ldA = [&](int bf, int mt, int ks) -> bf16x8 {
        const int r = wm + mt * 16 + l15;
        return *(const bf16x8*)
            &LDS[bf][0][r * GBK + (((ks * 4 + quad) ^ (r & 7)) << 3)];
    };
    auto ldB = [&](int bf, int nt, int ks) -> bf16x8 {
        const int r = wn + nt * 16 + l15;
        return *(const bf16x8*)
            &LDS[bf][1][r * GBK + (((ks * 4 + quad) ^ (r & 7)) << 3)];
    };

    // Prologue: A(0),B(0) -> buf0; B(1) -> buf1. vmcnt(4) = A(0),B(0) landed,
    // B(1) (4 loads) still in flight.
    stage(0, 0, 0, xb, m0, 0); stage(0, 0, 1, xb, m0, 0);
    stage(0, 1, 0, Wt, n0, 0); stage(0, 1, 1, Wt, n0, 0);
    stage(1, 1, 0, Wt, n0, 1); stage(1, 1, 1, Wt, n0, 1);
    WAIT_VM4();
    BAR();

    bf16x8 bv[4][2];  // B frags held in regs across the whole K-tile

    for (int t = 0; t < NKT; ++t) {
        const int buf = t & 1;

        // ---- phase 0: all 8 B-frags + A quadrant 0 (12 ds_read_b128) ----
        {
            #pragma unroll
            for (int nt = 0; nt < 4; ++nt)
                #pragma unroll
                for (int ks = 0; ks < 2; ++ks)
                    bv[nt][ks] = ldB(buf, nt, ks);
            bf16x8 av[2][2];
            #pragma unroll
            for (int ks = 0; ks < 2; ++ks) {
                av[0][ks] = ldA(buf, 0, ks);
                av[1][ks] = ldA(buf, 1, ks);
            }
            if (t + 1 < NKT) stage(buf ^ 1, 0, 0, xb, m0, t + 1);
            BAR();
            WAIT_LGKM0();
            __builtin_amdgcn_s_setprio(1);
            #pragma unroll
            for (int ks = 0; ks < 2; ++ks)
                #pragma unroll
                for (int mtl = 0; mtl < 2; ++mtl)
                    #pragma unroll
                    for (int nt = 0; nt < 4; ++nt)
                        acc[mtl][nt] = __builtin_amdgcn_mfma_f32_16x16x32_bf16(
                            av[mtl][ks], bv[nt][ks], acc[mtl][nt], 0, 0, 0);
            __builtin_amdgcn_s_setprio(0);
            BAR();
        }
        // ---- phases 1-3: A quadrant + one half-tile stage each ----
        // B(t+2) -> buf is legal: B(t) in buf fully consumed at phase 0.
        GPHASE(1, if (t + 1 < NKT) stage(buf ^ 1, 0, 1, xb, m0, t + 1));
        GPHASE(2, if (t + 2 < NKT) stage(buf, 1, 0, Wt, n0, t + 2));
        GPHASE(3, if (t + 2 < NKT) stage(buf, 1, 1, Wt, n0, t + 2));

        // One counted wait per K-tile: leave B(t+2) (4 loads) in flight;
        // guarantees A(t+1) + everything older landed. Drain at the tail.
        if (t < NKT - 2) { WAIT_VM4(); } else { WAIT_VM0(); }
    }

    // epilogue: C/D layout col=lane&15, row=quad*4+reg (m89/m91-verified)
    #pragma unroll
    for (int nt = 0; nt < 4; ++nt) {
        const int col = n0 + wn + nt * 16 + l15;
        const float bb = bias[col];
        #pragma unroll
        for (int mt = 0; mt < 8; ++mt) {
            const int rowb = m0 + wm + mt * 16 + quad * 4;
            #pragma unroll
            for (int i = 0; i < 4; ++i)
                out[(size_t)(rowb + i) * N_TOT + col] = acc[mt][nt][i] + bb;
        }
    }
}

// ---------------- fallback: round-4 fused kernel (proven correct) ----------------
#define FBM 256
#define FBN 128
#define FBKP 72

__global__ __launch_bounds__(256, 2) void gptq_gemm_fused(
    const float* __restrict__ x, const int* __restrict__ qweight,
    const int* __restrict__ qzeros, const float* __restrict__ scales,
    const int* __restrict__ g_idx, const float* __restrict__ bias,
    float* __restrict__ out)
{
    __shared__ __align__(16) unsigned short As[FBM * FBKP];
    __shared__ __align__(16) unsigned short Bt[FBN * FBKP];

    const int tid  = threadIdx.x;
    const int wave = tid >> 6;
    const int lane = tid & 63;
    const int n0 = blockIdx.x * FBN;
    const int m0 = blockIdx.y * FBM;
    const int wm = (wave >> 1) * 64;
    const int wn = (wave & 1) * 64;
    const int l15  = lane & 15;
    const int quad = lane >> 4;

    f32x4 acc[2][4][4];
    #pragma unroll
    for (int mi = 0; mi < 2; ++mi)
        #pragma unroll
        for (int i = 0; i < 4; ++i)
            #pragma unroll
            for (int j = 0; j < 4; ++j)
                acc[mi][i][j] = (f32x4)0.f;

    const int nb  = tid & 31;
    const int r   = tid >> 5;
    const int zsh = (nb & 7) * 4;

    for (int kt = 0; kt < K_TOT / 64; ++kt) {
        const int k0 = kt * 64;
        #pragma unroll
        for (int i = 0; i < 8; ++i) {
            const int c   = tid + i * 256;
            const int row = c >> 3;
            const int cb  = (c & 7) << 3;
            const float* xp = x + (size_t)(m0 + row) * K_TOT + (k0 + cb);
            const float4 f0 = *(const float4*)xp;
            const float4 f1 = *(const float4*)(xp + 4);
            bf16x8 v;
            v[0]=(__bf16)f0.x; v[1]=(__bf16)f0.y; v[2]=(__bf16)f0.z; v[3]=(__bf16)f0.w;
            v[4]=(__bf16)f1.x; v[5]=(__bf16)f1.y; v[6]=(__bf16)f1.z; v[7]=(__bf16)f1.w;
            *(bf16x8*)&As[row * FBKP + cb] = v;
        }
        const int g    = g_idx[k0];
        const int qrow = (k0 >> 3) + r;
        #pragma unroll
        for (int dn = 0; dn < 4; ++dn) {
            const int n  = nb + dn * 32;
            const int qi = qweight[(size_t)qrow * N_TOT + (n0 + n)];
            const int zi = qzeros[g * (N_TOT / 8) + ((n0 + n) >> 3)];
            const float s = scales[g * N_TOT + (n0 + n)];
            const float zs = (float)(((zi >> zsh) & 0xF) + 1) * s;
            bf16x8 v;
            #pragma unroll
            for (int j = 0; j < 8; ++j)
                v[j] = (__bf16)((float)((qi >> (4 * j)) & 0xF) * s - zs);
            *(bf16x8*)&Bt[n * FBKP + r * 8] = v;
        }
        __syncthreads();
        #pragma unroll
        for (int ks = 0; ks < 2; ++ks) {
            bf16x8 bvv[4];
            #pragma unroll
            for (int nt = 0; nt < 4; ++nt)
                bvv[nt] = *(const bf16x8*)&Bt[(wn + nt * 16 + l15) * FBKP + ks * 32 + quad * 8];
            #pragma unroll
            for (int mi = 0; mi < 2; ++mi) {
                bf16x8 av[4];
                #pragma unroll
                for (int mt = 0; mt < 4; ++mt)
                    av[mt] = *(const bf16x8*)&As[(mi * 128 + wm + mt * 16 + l15) * FBKP + ks * 32 + quad * 8];
                #pragma unroll
                for (int mt = 0; mt < 4; ++mt)
                    #pragma unroll
                    for (int nt = 0; nt < 4; ++nt)
                        acc[mi][mt][nt] = __builtin_amdgcn_mfma_f32_16x16x32_bf16(
                            av[mt], bvv[nt], acc[mi][mt][nt], 0, 0, 0);
            }
        }
        __syncthreads();
    }
    #pragma unroll
    for (int mi = 0; mi < 2; ++mi)
        #pragma unroll
        for (int nt = 0; nt < 4; ++nt) {
            const int col = n0 + wn + nt * 16 + l15;
            const float bvv = bias[col];
            #pragma unroll
            for (int mt = 0; mt < 4; ++mt) {
                const int rowb = m0 + mi * 128 + wm + mt * 16 + quad * 4;
                #pragma unroll
                for (int i = 0; i < 4; ++i)
                    out[(size_t)(rowb + i) * N_TOT + col] = acc[mi][mt][nt][i] + bvv;
            }
        }
}

extern "C" void kernel_launch(void* const* d_in, const int* in_sizes, int n_in,
                              void* d_out, int out_size, void* d_ws, size_t ws_size,
                              hipStream_t stream) {
    const float* x  = (const float*)d_in[0];
    const int*   qw = (const int*)d_in[1];
    const int*   qz = (const int*)d_in[2];
    const float* sc = (const float*)d_in[3];
    const int*   gi = (const int*)d_in[4];
    const float* bs = (const float*)d_in[5];
    float* out = (float*)d_out;

    const size_t xb_bytes = (size_t)M_TOT * K_TOT * 2;   // 67,108,864
    const size_t wt_bytes = (size_t)N_TOT * K_TOT * 2;   // 33,554,432

    if (ws_size >= xb_bytes + wt_bytes) {
        __bf16* xb = (__bf16*)d_ws;
        __bf16* Wt = (__bf16*)((char*)d_ws + xb_bytes);
        cast_x<<<dim3((M_TOT * K_TOT) / (256 * 8)), dim3(256), 0, stream>>>(x, xb);
        dequant_w<<<dim3(K_TOT / 64, N_TOT / 64), dim3(256), 0, stream>>>(qw, qz, sc, gi, Wt);
        gemm8p<<<dim3((M_TOT / GBM) * (N_TOT / GBN)), dim3(512), 0, stream>>>(xb, Wt, bs, out);
    } else {
        gptq_gemm_fused<<<dim3(N_TOT / FBN, M_TOT / FBM), dim3(256), 0, stream>>>(
            x, qw, qz, sc, gi, bs, out);
    }
}